// Round 1
// baseline (378.318 us; speedup 1.0000x reference)
//
#include <hip/hip_runtime.h>

// Quantum feature map: 20 qubits, 4 layers of (RX·RY per wire + CNOT chain), <Z_i> outputs.
// wire w <-> bit (19-w). CNOT chain == gray-code permutation state'[y] = state[y ^ (y>>1)],
// folded into the next read stage / final expectation pass (never a standalone pass).

#define NW 20

__device__ __forceinline__ void apply_gate(float2& a0, float2& a1,
                                           float2 u00, float2 u01,
                                           float2 u10, float2 u11) {
    float2 b0, b1;
    b0.x = u00.x*a0.x - u00.y*a0.y + u01.x*a1.x - u01.y*a1.y;
    b0.y = u00.x*a0.y + u00.y*a0.x + u01.x*a1.y + u01.y*a1.x;
    b1.x = u10.x*a0.x - u10.y*a0.y + u11.x*a1.x - u11.y*a1.y;
    b1.y = u10.x*a0.y + u10.y*a0.x + u11.x*a1.y + u11.y*a1.x;
    a0 = b0; a1 = b1;
}

// U = RY(x)*RX(x), both with half-angle h = x/2.
__global__ void prep_gates(const float* __restrict__ x, float2* __restrict__ G,
                           float* __restrict__ out) {
    int w = threadIdx.x;
    if (w < NW) {
        float h = 0.5f * x[w];
        float c = cosf(h), s = sinf(h);
        float cc = c*c, ss = s*s, cs = c*s;
        G[w*4+0] = make_float2(cc,  ss);
        G[w*4+1] = make_float2(-cs, -cs);
        G[w*4+2] = make_float2(cs,  -cs);
        G[w*4+3] = make_float2(cc,  -ss);
        out[w] = 0.0f;   // zero d_out for the final atomic accumulation
    }
}

__global__ void init_state(float2* __restrict__ s) {
    unsigned i = blockIdx.x * blockDim.x + threadIdx.x;
    s[i] = make_float2(i == 0 ? 1.0f : 0.0f, 0.0f);
}

// Stage A: gates on logical bits 0..11 (wires 19..8).
// PERM=1: also materialize the pending gray permutation from the previous layer:
//   logical y=(H<<12)|l lives at physical ((H^(H>>1))<<12) | ((l^(l>>1)) ^ ((H&1)<<11)).
// Loads are fully contiguous; the un-gray happens in LDS addressing.
template<int PERM>
__global__ __launch_bounds__(256) void stageA(const float2* __restrict__ src,
                                              float2* __restrict__ dst,
                                              const float2* __restrict__ G) {
    __shared__ float2 lds[4096];
    unsigned H   = blockIdx.x;                    // logical high 8 bits
    unsigned Hp  = PERM ? (H ^ (H >> 1)) : H;     // physical high 8 bits
    unsigned inj = PERM ? ((H & 1u) << 11) : 0u;
    unsigned t = threadIdx.x;

    const float4* srcv = (const float4*)(src + ((size_t)Hp << 12));
    #pragma unroll
    for (int i = 0; i < 8; i++) {
        unsigned j = i*256u + t;          // float4 index (2 complex), 2048 total
        float4 v = srcv[j];
        unsigned pi = j*2u;               // physical low complex index (even)
        unsigned l;
        if (PERM) {
            unsigned xx = pi ^ inj;       // invgray over 12 bits
            xx ^= xx >> 1; xx ^= xx >> 2; xx ^= xx >> 4; xx ^= xx >> 8;
            l = xx & 4095u;
        } else {
            l = pi;
        }
        lds[l]     = make_float2(v.x, v.y);
        lds[l ^ 1] = make_float2(v.z, v.w);   // invgray(pi^1)=l^1 (GF2-linear)
    }
    __syncthreads();

    for (int p = 0; p < 12; p++) {
        int w = 19 - p;
        float2 u00 = G[w*4+0], u01 = G[w*4+1], u10 = G[w*4+2], u11 = G[w*4+3];
        unsigned mlow = (1u << p) - 1u;
        #pragma unroll
        for (int i = 0; i < 8; i++) {
            unsigned k  = i*256u + t;                       // pair index 0..2047
            unsigned l0 = ((k & ~mlow) << 1) | (k & mlow);  // insert 0 at bit p
            unsigned l1 = l0 | (1u << p);
            float2 a0 = lds[l0], a1 = lds[l1];
            apply_gate(a0, a1, u00, u01, u10, u11);
            lds[l0] = a0; lds[l1] = a1;
        }
        __syncthreads();
    }

    float4* dstv = (float4*)(dst + ((size_t)H << 12));   // logical-contiguous write
    #pragma unroll
    for (int i = 0; i < 8; i++) {
        unsigned j = i*256u + t;
        float2 e0 = lds[2*j], e1 = lds[2*j + 1];
        dstv[j] = make_float4(e0.x, e0.y, e1.x, e1.y);
    }
}

// Stage B: gates on bits 12..19 (wires 7..0). Subcube = 16 consecutive low offsets
// x 256 high combos; in-place (no cross-block movement). No pending permutation here.
__global__ __launch_bounds__(256) void stageB(float2* __restrict__ st,
                                              const float2* __restrict__ G) {
    __shared__ float2 lds[4096];
    unsigned b = blockIdx.x;             // low bits 4..11
    unsigned t = threadIdx.x;

    #pragma unroll
    for (int i = 0; i < 8; i++) {
        unsigned j  = i*256u + t;        // float4 index; ci = 2j
        unsigned ci = 2u*j;
        unsigned h = ci >> 4, m = ci & 15u;
        const float4* g = (const float4*)(st + (((size_t)h << 12) | (b << 4) | m));
        float4 v = *g;
        lds[ci]     = make_float2(v.x, v.y);
        lds[ci + 1] = make_float2(v.z, v.w);
    }
    __syncthreads();

    for (int q = 0; q < 8; q++) {
        int w = 7 - q;                   // bit p=12+q  <->  wire 7-q
        float2 u00 = G[w*4+0], u01 = G[w*4+1], u10 = G[w*4+2], u11 = G[w*4+3];
        unsigned mq = (1u << q) - 1u;
        #pragma unroll
        for (int i = 0; i < 8; i++) {
            unsigned k  = i*256u + t;    // 0..2047
            unsigned m  = k & 15u, hk = k >> 4;              // hk: 7 bits
            unsigned h0 = ((hk & ~mq) << 1) | (hk & mq);
            unsigned l0 = (h0 << 4) | m;
            unsigned l1 = ((h0 | (1u << q)) << 4) | m;
            float2 a0 = lds[l0], a1 = lds[l1];
            apply_gate(a0, a1, u00, u01, u10, u11);
            lds[l0] = a0; lds[l1] = a1;
        }
        __syncthreads();
    }

    #pragma unroll
    for (int i = 0; i < 8; i++) {
        unsigned j  = i*256u + t;
        unsigned ci = 2u*j;
        unsigned h = ci >> 4, m = ci & 15u;
        float4* g = (float4*)(st + (((size_t)h << 12) | (b << 4) | m));
        float2 e0 = lds[ci], e1 = lds[ci + 1];
        *g = make_float4(e0.x, e0.y, e1.x, e1.y);
    }
}

// Final pass: one pending gray permutation folded in: logical y = prefixxor(x).
// out[w] = sum over states sign(bit(19-w) of y) * |amp|^2.
__global__ __launch_bounds__(256) void expect_z(const float2* __restrict__ st,
                                                float* __restrict__ out) {
    float acc[NW];
    #pragma unroll
    for (int w = 0; w < NW; w++) acc[w] = 0.0f;

    unsigned gid = blockIdx.x * 256u + threadIdx.x;   // 65536 threads
    const float4* sv = (const float4*)st;
    #pragma unroll
    for (int i = 0; i < 8; i++) {
        unsigned j = i*65536u + gid;                  // float4 idx, 524288 total
        float4 v = sv[j];
        unsigned x0 = 2u*j;
        #pragma unroll
        for (int e = 0; e < 2; e++) {
            unsigned x = x0 + e;
            float re = e ? v.z : v.x, im = e ? v.w : v.y;
            float p = re*re + im*im;
            unsigned y = x;                            // invgray20
            y ^= y >> 1; y ^= y >> 2; y ^= y >> 4; y ^= y >> 8; y ^= y >> 16;
            #pragma unroll
            for (int w = 0; w < NW; w++) {
                unsigned bit = (y >> (19 - w)) & 1u;
                // p >= 0: OR-ing the sign bit negates when bit==1
                acc[w] += __uint_as_float(__float_as_uint(p) | (bit << 31));
            }
        }
    }

    #pragma unroll
    for (int w = 0; w < NW; w++) {
        float v = acc[w];
        for (int off = 32; off > 0; off >>= 1) v += __shfl_down(v, off, 64);
        if ((threadIdx.x & 63u) == 0u) atomicAdd(&out[w], v);
    }
}

extern "C" void kernel_launch(void* const* d_in, const int* in_sizes, int n_in,
                              void* d_out, int out_size, void* d_ws, size_t ws_size,
                              hipStream_t stream) {
    (void)in_sizes; (void)n_in; (void)out_size; (void)ws_size;
    const float* x = (const float*)d_in[0];
    float* out = (float*)d_out;

    char* ws = (char*)d_ws;
    float2* gates = (float2*)ws;                                   // 640 B
    float2* buf0  = (float2*)(ws + 65536);                         // 8 MB
    float2* buf1  = (float2*)(ws + 65536 + (size_t)(8u << 20));    // 8 MB

    prep_gates<<<1, 32, 0, stream>>>(x, gates, out);
    init_state<<<4096, 256, 0, stream>>>(buf0);

    float2* src = buf0;
    float2* dst = buf1;
    for (int l = 0; l < 4; l++) {
        if (l == 0) stageA<0><<<256, 256, 0, stream>>>(src, dst, gates);
        else        stageA<1><<<256, 256, 0, stream>>>(src, dst, gates);
        stageB<<<256, 256, 0, stream>>>(dst, gates);
        float2* tmp = src; src = dst; dst = tmp;
    }
    expect_z<<<256, 256, 0, stream>>>(src, out);
}

// Round 2
// 77.152 us; speedup vs baseline: 4.9036x; 4.9036x over previous
//
#include <hip/hip_runtime.h>

// 20-qubit feature map: 4 layers of (RX·RY per wire + CNOT chain), <Z_i> outputs.
// wire w <-> bit (19-w). CNOT chain: post-perm logical index y holds pre-perm amp
// at gray(y) = y ^ (y>>1); perm is always folded into the next read (or the final
// expectation) rather than materialized.
// Layer 1 acting on |0..0> yields a product state, computed directly inside the
// first stageA (MODE=0). Sequence:
//   prep -> A<0>(init+L2 low) -> B<0>(L2 high) -> A<1>(L3) -> B<0> -> A<1>(L4)
//        -> B<1>(L4 high + fused expectation) -> reduce

#define NW 20

__device__ __forceinline__ float2 cmul(float2 a, float2 b) {
    return make_float2(a.x*b.x - a.y*b.y, a.x*b.y + a.y*b.x);
}

__device__ __forceinline__ void apply_gate(float2& a0, float2& a1,
                                           float2 u00, float2 u01,
                                           float2 u10, float2 u11) {
    float2 b0, b1;
    b0.x = u00.x*a0.x - u00.y*a0.y + u01.x*a1.x - u01.y*a1.y;
    b0.y = u00.x*a0.y + u00.y*a0.x + u01.x*a1.y + u01.y*a1.x;
    b1.x = u10.x*a0.x - u10.y*a0.y + u11.x*a1.x - u11.y*a1.y;
    b1.y = u10.x*a0.y + u10.y*a0.x + u11.x*a1.y + u11.y*a1.x;
    a0 = b0; a1 = b1;
}

// LDS swizzle: inject element bits 4..6 into bits 1..3 -> every gate step lands at
// the 4-way (minimum) bank aliasing for b64 access. Involution, pairing-safe.
__device__ __forceinline__ unsigned swz(unsigned l) { return l ^ ((l >> 3) & 14u); }

// U = RY(x)*RX(x), half-angle h = x/2. G[w*4 + r*2 + c] = U^w[r][c].
__global__ void prep_gates(const float* __restrict__ x, float2* __restrict__ G) {
    int w = threadIdx.x;
    if (w < NW) {
        float h = 0.5f * x[w];
        float c = cosf(h), s = sinf(h);
        float cc = c*c, ss = s*s, cs = c*s;
        G[w*4+0] = make_float2(cc,  ss);
        G[w*4+1] = make_float2(-cs, -cs);
        G[w*4+2] = make_float2(cs,  -cs);
        G[w*4+3] = make_float2(cc,  -ss);
    }
}

// Stage A: gates on bits 0..11 (wires 19..8). 1024 thr/block, 4 amps/thread.
// MODE 0: compute product state (layer-1 output) directly, perm folded: the amp at
//         logical Y is Prod_b U^{19-b}[z_b][0] with z = gray20(Y).
// MODE 1: load from src with pending gray perm folded (quad load + in-quad permute).
// Gates on bits 0,1 applied in registers; bits 2..11 via swizzled LDS; p=11 step
// stores straight to dst (logical order).
template<int MODE>
__global__ __launch_bounds__(1024) void stageA(const float2* __restrict__ src,
                                               float2* __restrict__ dst,
                                               const float2* __restrict__ G) {
    __shared__ float4 ldsv[2048];
    float2* lds = (float2*)ldsv;
    unsigned t   = threadIdx.x;
    unsigned H   = blockIdx.x;            // logical high 8 bits
    unsigned Hp  = H ^ (H >> 1);          // physical high 8 bits
    unsigned inj = (H & 1u) << 11;
    unsigned l   = t * 4u;                // logical low-12 base (4 consecutive amps)
    unsigned gl  = (l ^ (l >> 1)) ^ inj;  // low-12 of gray20(Y) for k=0

    float2 a0, a1, a2, a3;
    if (MODE == 1) {
        // z_k = (Hp<<12) | (gl ^ gray(k)); all four live in one aligned 32B quad.
        const float4* qp = (const float4*)(src + ((size_t)Hp << 12) + (gl & ~3u));
        float4 q0 = qp[0], q1 = qp[1];
        float2 e0 = make_float2(q0.x, q0.y), e1 = make_float2(q0.z, q0.w);
        float2 e2 = make_float2(q1.x, q1.y), e3 = make_float2(q1.z, q1.w);
        // a[k] = e[(gl & 3) ^ gray(k)] ; branchless XOR-permute
        bool s1 = (gl & 1u) != 0u, s2 = (gl & 2u) != 0u;
        float2 f0 = s1 ? e1 : e0, f1 = s1 ? e0 : e1;
        float2 f2 = s1 ? e3 : e2, f3 = s1 ? e2 : e3;
        float2 g0 = s2 ? f2 : f0, g1 = s2 ? f3 : f1;
        float2 g2 = s2 ? f0 : f2, g3 = s2 ? f1 : f3;
        a0 = g0; a1 = g1; a2 = g3; a3 = g2;   // gray(k): 0,1,3,2
    } else {
        // product over bits 2..19 of z (common to the quad)
        float2 P = make_float2(1.0f, 0.0f);
        #pragma unroll
        for (int b = 12; b <= 19; b++)
            P = cmul(P, G[(19-b)*4 + (int)((Hp >> (b-12)) & 1u)*2]);
        #pragma unroll
        for (int b = 2; b <= 11; b++)
            P = cmul(P, G[(19-b)*4 + (int)((gl >> b) & 1u)*2]);
        float2 aa[4];
        #pragma unroll
        for (int k = 0; k < 4; k++) {
            unsigned mm = (gl ^ (unsigned)(k ^ (k >> 1))) & 3u;
            float2 f = cmul(G[19*4 + (int)(mm & 1u)*2], G[18*4 + (int)((mm >> 1) & 1u)*2]);
            aa[k] = cmul(P, f);
        }
        a0 = aa[0]; a1 = aa[1]; a2 = aa[2]; a3 = aa[3];
    }

    // p=0 (wire 19): pairs differ in bit0 -> (a0,a1),(a2,a3)
    {
        float2 u00 = G[76], u01 = G[77], u10 = G[78], u11 = G[79];
        apply_gate(a0, a1, u00, u01, u10, u11);
        apply_gate(a2, a3, u00, u01, u10, u11);
    }
    // p=1 (wire 18): pairs differ in bit1 -> (a0,a2),(a1,a3)
    {
        float2 u00 = G[72], u01 = G[73], u10 = G[74], u11 = G[75];
        apply_gate(a0, a2, u00, u01, u10, u11);
        apply_gate(a1, a3, u00, u01, u10, u11);
    }
    lds[swz(l+0u)] = a0; lds[swz(l+1u)] = a1;
    lds[swz(l+2u)] = a2; lds[swz(l+3u)] = a3;
    __syncthreads();

    #pragma unroll
    for (int p = 2; p <= 11; p++) {
        int w = 19 - p;
        float2 u00 = G[w*4], u01 = G[w*4+1], u10 = G[w*4+2], u11 = G[w*4+3];
        unsigned mask = (1u << p) - 1u;
        #pragma unroll
        for (int i = 0; i < 2; i++) {
            unsigned kk = (unsigned)i*1024u + t;                 // pair idx 0..2047
            unsigned l0 = ((kk & ~mask) << 1) | (kk & mask);
            unsigned l1 = l0 | (1u << p);
            unsigned s0 = swz(l0), s1i = swz(l1);
            float2 b0 = lds[s0], b1 = lds[s1i];
            apply_gate(b0, b1, u00, u01, u10, u11);
            if (p < 11) { lds[s0] = b0; lds[s1i] = b1; }
            else {       // p=11: l0 = kk, l1 = kk+2048 ; store direct, coalesced
                dst[((size_t)H << 12) + l0] = b0;
                dst[((size_t)H << 12) + l1] = b1;
            }
        }
        if (p < 11) __syncthreads();
    }
}

// Stage B: gates on bits 12..19 (wires 7..0); in-place, logical indexing kept.
// Thread owns amps at h in {2hk, 2hk+1, 2hk+128, 2hk+129} (x fixed low bits), so
// gates on h-bit0 (wire 7) and h-bit7 (wire 0) run in registers; bits 1..6 via LDS.
// FUSE=1: final layer -> fold last gray perm and accumulate <Z_w> partials.
template<int FUSE>
__global__ __launch_bounds__(1024) void stageB(float2* __restrict__ st,
                                               const float2* __restrict__ G,
                                               float* __restrict__ partial) {
    __shared__ float4 ldsv[2048];
    float2* lds = (float2*)ldsv;
    unsigned t  = threadIdx.x;
    unsigned bb = blockIdx.x;             // bits 4..11 of the global index
    unsigned m  = t & 15u, hk = t >> 4;   // m: bits 0..3 ; hk: 6 bits
    unsigned h0 = hk << 1;
    unsigned hsA = h0, hsB = h0 | 1u, hsC = h0 | 128u, hsD = h0 | 129u;
    size_t base = ((size_t)bb << 4) | m;
    float2 a0 = st[((size_t)hsA << 12) | base];
    float2 a1 = st[((size_t)hsB << 12) | base];
    float2 a2 = st[((size_t)hsC << 12) | base];
    float2 a3 = st[((size_t)hsD << 12) | base];

    // q=0 (wire 7, h bit0): (a0,a1),(a2,a3)
    {
        float2 u00 = G[28], u01 = G[29], u10 = G[30], u11 = G[31];
        apply_gate(a0, a1, u00, u01, u10, u11);
        apply_gate(a2, a3, u00, u01, u10, u11);
    }
    // q=7 (wire 0, h bit7): (a0,a2),(a1,a3)
    {
        float2 u00 = G[0], u01 = G[1], u10 = G[2], u11 = G[3];
        apply_gate(a0, a2, u00, u01, u10, u11);
        apply_gate(a1, a3, u00, u01, u10, u11);
    }
    lds[(hsA << 4) | m] = a0; lds[(hsB << 4) | m] = a1;
    lds[(hsC << 4) | m] = a2; lds[(hsD << 4) | m] = a3;
    __syncthreads();

    #pragma unroll
    for (int q = 1; q <= 5; q++) {
        int w = 7 - q;
        float2 u00 = G[w*4], u01 = G[w*4+1], u10 = G[w*4+2], u11 = G[w*4+3];
        unsigned mq = (1u << q) - 1u;
        #pragma unroll
        for (int i = 0; i < 2; i++) {
            unsigned kk = (unsigned)i*1024u + t;
            unsigned mm = kk & 15u, hh = kk >> 4;            // hh: 7 bits
            unsigned hA = ((hh & ~mq) << 1) | (hh & mq);
            unsigned ci0 = (hA << 4) | mm, ci1 = ci0 | (1u << (4 + q));
            float2 b0 = lds[ci0], b1 = lds[ci1];
            apply_gate(b0, b1, u00, u01, u10, u11);
            lds[ci0] = b0; lds[ci1] = b1;
        }
        __syncthreads();
    }

    // q=6 tail (wire 1, h bit6): keep results in registers.
    float acc[NW];
    if (FUSE) {
        #pragma unroll
        for (int w = 0; w < NW; w++) acc[w] = 0.0f;
    }
    {
        float2 u00 = G[4], u01 = G[5], u10 = G[6], u11 = G[7];
        #pragma unroll
        for (int i = 0; i < 2; i++) {
            unsigned kk = (unsigned)i*1024u + t;
            unsigned mm = kk & 15u, hh = kk >> 4;
            unsigned hA = ((hh & ~63u) << 1) | (hh & 63u);
            unsigned ci0 = (hA << 4) | mm, ci1 = ci0 | (1u << 10);
            float2 b0 = lds[ci0], b1 = lds[ci1];
            apply_gate(b0, b1, u00, u01, u10, u11);
            if (!FUSE) {
                st[((size_t)(ci0 >> 4) << 12) | ((size_t)bb << 4) | mm] = b0;
                st[((size_t)(ci1 >> 4) << 12) | ((size_t)bb << 4) | mm] = b1;
            } else {
                #pragma unroll
                for (int e = 0; e < 2; e++) {
                    unsigned ci = e ? ci1 : ci0;
                    float2 bv  = e ? b1 : b0;
                    unsigned Y = ((ci >> 4) << 12) | (bb << 4) | mm;
                    unsigned y = Y;                       // final perm: y' = invgray(Y)
                    y ^= y >> 1; y ^= y >> 2; y ^= y >> 4; y ^= y >> 8; y ^= y >> 16;
                    float p = bv.x*bv.x + bv.y*bv.y;
                    #pragma unroll
                    for (int w = 0; w < NW; w++) {
                        unsigned bit = (y >> (19 - w)) & 1u;
                        acc[w] += __uint_as_float(__float_as_uint(p) | (bit << 31));
                    }
                }
            }
        }
    }

    if (FUSE) {
        __syncthreads();                    // all LDS gate reads done; reuse as scratch
        float* redf = (float*)ldsv;
        #pragma unroll
        for (int w = 0; w < NW; w++) {
            float v = acc[w];
            #pragma unroll
            for (int off = 32; off; off >>= 1) v += __shfl_down(v, off, 64);
            if ((t & 63u) == 0u) redf[(t >> 6)*NW + w] = v;
        }
        __syncthreads();
        if (t < NW) {
            float s = 0.0f;
            #pragma unroll
            for (int wv = 0; wv < 16; wv++) s += redf[wv*NW + (int)t];
            partial[bb*NW + t] = s;
        }
    }
}

__global__ __launch_bounds__(256) void reduce_out(const float* __restrict__ partial,
                                                  float* __restrict__ out) {
    __shared__ float red[4*NW];
    unsigned t = threadIdx.x;
    float vals[NW];
    #pragma unroll
    for (int w = 0; w < NW; w++) vals[w] = partial[t*NW + w];
    #pragma unroll
    for (int w = 0; w < NW; w++) {
        float v = vals[w];
        #pragma unroll
        for (int off = 32; off; off >>= 1) v += __shfl_down(v, off, 64);
        if ((t & 63u) == 0u) red[(t >> 6)*NW + w] = v;
    }
    __syncthreads();
    if (t < NW) out[t] = red[t] + red[NW+t] + red[2*NW+t] + red[3*NW+t];
}

extern "C" void kernel_launch(void* const* d_in, const int* in_sizes, int n_in,
                              void* d_out, int out_size, void* d_ws, size_t ws_size,
                              hipStream_t stream) {
    (void)in_sizes; (void)n_in; (void)out_size; (void)ws_size;
    const float* x = (const float*)d_in[0];
    float* out = (float*)d_out;

    char* ws = (char*)d_ws;
    float2* gates   = (float2*)ws;                               // 640 B
    float*  partial = (float*)(ws + 1024);                       // 256*20*4 = 20 KB
    float2* buf0    = (float2*)(ws + 65536);                     // 8 MB
    float2* buf1    = (float2*)(ws + 65536 + (size_t)(8u << 20));// 8 MB

    prep_gates<<<1, 32, 0, stream>>>(x, gates);
    // layer 1 absorbed into init; layer 2:
    stageA<0><<<256, 1024, 0, stream>>>(buf1 /*unused*/, buf0, gates);
    stageB<0><<<256, 1024, 0, stream>>>(buf0, gates, nullptr);
    // layer 3:
    stageA<1><<<256, 1024, 0, stream>>>(buf0, buf1, gates);
    stageB<0><<<256, 1024, 0, stream>>>(buf1, gates, nullptr);
    // layer 4 (+ fused expectation):
    stageA<1><<<256, 1024, 0, stream>>>(buf1, buf0, gates);
    stageB<1><<<256, 1024, 0, stream>>>(buf0, gates, partial);
    reduce_out<<<1, 256, 0, stream>>>(partial, out);
}

// Round 4
// 72.754 us; speedup vs baseline: 5.1999x; 1.0604x over previous
//
#include <hip/hip_runtime.h>

// 20-qubit feature map: 4 layers of (RX·RY per wire + CNOT chain), <Z_i> outputs.
// wire w <-> bit (19-w). CNOT chain == gray perm: new[y] = old[y ^ (y>>1)], always
// folded into the next read (stageA MODE1) or the final expectation (stageB FUSE).
// Layer 1 on |0..0> = product state, computed in-register in stageA MODE0.
//
// Block engine: 512 thr/block, 8 amps/thread in registers. Gates apply on the 3
// register bits; shfl_xor butterfly swaps rotate lane bits into registers (no
// barrier); ONE LDS round trip (1 barrier) for cross-wave bits.
// R4 fixes vs R3: (1) butterfly send-select was inverted; (2) stageB load used
// wv<<6 for an 8-bit field (must be wv<<5).

#define NW 20

__device__ __forceinline__ float2 cmul(float2 a, float2 b) {
    return make_float2(a.x*b.x - a.y*b.y, a.x*b.y + a.y*b.x);
}

__device__ __forceinline__ void apply_gate(float2& a0, float2& a1,
                                           float2 u00, float2 u01,
                                           float2 u10, float2 u11) {
    float2 b0, b1;
    b0.x = u00.x*a0.x - u00.y*a0.y + u01.x*a1.x - u01.y*a1.y;
    b0.y = u00.x*a0.y + u00.y*a0.x + u01.x*a1.y + u01.y*a1.x;
    b1.x = u10.x*a0.x - u10.y*a0.y + u11.x*a1.x - u11.y*a1.y;
    b1.y = u10.x*a0.y + u10.y*a0.x + u11.x*a1.y + u11.y*a1.x;
    a0 = b0; a1 = b1;
}

__device__ __forceinline__ float2 shflx(float2 v, int m) {
    float2 r;
    r.x = __shfl_xor(v.x, m, 64);
    r.y = __shfl_xor(v.y, m, 64);
    return r;
}

// Apply the 2x2 gate (at Gw) pairing amps that differ in reg-bit A.
template<int A>
__device__ __forceinline__ void gate_regbit(float2 (&amp)[8], const float2* __restrict__ Gw) {
    float2 u00 = Gw[0], u01 = Gw[1], u10 = Gw[2], u11 = Gw[3];
    #pragma unroll
    for (int r = 0; r < 8; r++)
        if (!(r & (1 << A)))
            apply_gate(amp[r], amp[r | (1 << A)], u00, u01, u10, u11);
}

// Swap reg-bit A with the lane bit selected by mask LM (butterfly exchange).
// V(pa,pl) at (reg=pa,lane=pl) moves to (reg=pl,lane=pa): the off-diagonal pair
// (reg=1,lane=0) <-> (reg=0,lane=1) swaps; lane_b=0 sends hi, lane_b=1 sends lo.
template<int A, int LM>
__device__ __forceinline__ void swap_reg_lane(float2 (&amp)[8], unsigned lane) {
    bool hb = (lane & (unsigned)LM) != 0u;
    #pragma unroll
    for (int r = 0; r < 8; r++) {
        if (!(r & (1 << A))) {
            float2 lo = amp[r], hi = amp[r | (1 << A)];
            float2 xs = hb ? lo : hi;          // FIX: send what the partner needs
            float2 ys = shflx(xs, LM);
            amp[r]            = hb ? ys : lo;  // b=1 receives into lo-slot
            amp[r | (1 << A)] = hb ? hi : ys;  // b=0 receives into hi-slot
        }
    }
}

// U = RY(x)*RX(x), half-angle h = x/2. G[w*4 + r*2 + c] = U^w[r][c].
__global__ void prep_gates(const float* __restrict__ x, float2* __restrict__ G) {
    int w = threadIdx.x;
    if (w < NW) {
        float h = 0.5f * x[w];
        float c = cosf(h), s = sinf(h);
        float cc = c*c, ss = s*s, cs = c*s;
        G[w*4+0] = make_float2(cc,  ss);
        G[w*4+1] = make_float2(-cs, -cs);
        G[w*4+2] = make_float2(cs,  -cs);
        G[w*4+3] = make_float2(cc,  -ss);
    }
}

// Stage A: gates on bits 0..11 (wires 19..8). Block = logical high byte H.
// Thread layout: regs = bits 0..2, lane = bits 3..8, wave = bits 9..11.
// MODE 0: product state (layer-1 output) computed directly, layer-1 perm folded.
// MODE 1: read src with pending gray perm folded (aligned 64B group, fixed permute).
template<int MODE>
__global__ __launch_bounds__(512) void stageA(const float2* __restrict__ src,
                                              float2* __restrict__ dst,
                                              const float2* __restrict__ G) {
    __shared__ float2 lds[4096];
    const unsigned t = threadIdx.x;
    const unsigned lane = t & 63u, wv = t >> 6;
    const unsigned H   = blockIdx.x;
    const unsigned Hp  = H ^ (H >> 1);
    const unsigned inj = (H & 1u) << 11;
    const unsigned lb  = (wv << 9) | (lane << 3);        // logical low-12 base (8-aligned)
    const unsigned gb  = (lb ^ (lb >> 1)) ^ inj;         // gray12(lb)^inj; low3 = (lane&1)<<2

    float2 amp[8];
    if (MODE == 1) {
        // phys = gb ^ gray3(k): all 8 amps live in the aligned 64B group at gb&~7.
        const float4* q = (const float4*)(src + ((size_t)Hp << 12) + (gb & ~7u));
        float4 q0 = q[0], q1 = q[1], q2 = q[2], q3 = q[3];
        float2 e0 = make_float2(q0.x,q0.y), e1 = make_float2(q0.z,q0.w);
        float2 e2 = make_float2(q1.x,q1.y), e3 = make_float2(q1.z,q1.w);
        float2 e4 = make_float2(q2.x,q2.y), e5 = make_float2(q2.z,q2.w);
        float2 e6 = make_float2(q3.x,q3.y), e7 = make_float2(q3.z,q3.w);
        bool f = (gb & 4u) != 0u;     // amp[k] = e[(f?4:0) ^ gray3(k)]
        amp[0] = f ? e4 : e0;  amp[1] = f ? e5 : e1;
        amp[2] = f ? e7 : e3;  amp[3] = f ? e6 : e2;
        amp[4] = f ? e2 : e6;  amp[5] = f ? e3 : e7;
        amp[6] = f ? e1 : e5;  amp[7] = f ? e0 : e4;
    } else {
        // amp(Y) = prod_b U^{19-b}[z_b][0], z = gray20(Y); z low-12 = gb ^ gray3(k).
        float2 P = make_float2(1.0f, 0.0f);
        #pragma unroll
        for (int b = 12; b <= 19; b++)
            P = cmul(P, G[(19-b)*4 + (int)((Hp >> (b-12)) & 1u)*2]);
        #pragma unroll
        for (int b = 3; b <= 11; b++)
            P = cmul(P, G[(19-b)*4 + (int)((gb >> b) & 1u)*2]);
        float2 Tt[8];
        #pragma unroll
        for (int j = 0; j < 8; j++) {
            float2 v = cmul(G[18*4 + ((j>>1)&1)*2], G[19*4 + (j&1)*2]);
            v = cmul(G[17*4 + ((j>>2)&1)*2], v);
            Tt[j] = cmul(P, v);
        }
        bool f = (gb & 4u) != 0u;     // amp[k] = Tt[(f?4:0) ^ gray3(k)]
        amp[0] = f ? Tt[4] : Tt[0];  amp[1] = f ? Tt[5] : Tt[1];
        amp[2] = f ? Tt[7] : Tt[3];  amp[3] = f ? Tt[6] : Tt[2];
        amp[4] = f ? Tt[2] : Tt[6];  amp[5] = f ? Tt[3] : Tt[7];
        amp[6] = f ? Tt[1] : Tt[5];  amp[7] = f ? Tt[0] : Tt[4];
    }

    // bits 0,1,2 (wires 19,18,17) on regs
    gate_regbit<0>(amp, G + 19*4);
    gate_regbit<1>(amp, G + 18*4);
    gate_regbit<2>(amp, G + 17*4);
    // regs <-> lane bits 0..2 (amp bits 3..5)
    swap_reg_lane<0,1>(amp, lane);
    swap_reg_lane<1,2>(amp, lane);
    swap_reg_lane<2,4>(amp, lane);
    gate_regbit<0>(amp, G + 16*4);   // bit 3
    gate_regbit<1>(amp, G + 15*4);   // bit 4
    gate_regbit<2>(amp, G + 14*4);   // bit 5
    // regs <-> lane bits 3..5 (amp bits 6..8)
    swap_reg_lane<0,8>(amp, lane);
    swap_reg_lane<1,16>(amp, lane);
    swap_reg_lane<2,32>(amp, lane);
    gate_regbit<0>(amp, G + 13*4);   // bit 6
    gate_regbit<1>(amp, G + 12*4);   // bit 7
    gate_regbit<2>(amp, G + 11*4);   // bit 8
    // LDS exchange: bring bits 9..11 into regs (amp low-6 == lane at this point)
    #pragma unroll
    for (int k = 0; k < 8; k++) lds[(wv << 9) | ((unsigned)k << 6) | lane] = amp[k];
    __syncthreads();
    #pragma unroll
    for (int k = 0; k < 8; k++) amp[k] = lds[((unsigned)k << 9) | (wv << 6) | lane];
    gate_regbit<0>(amp, G + 10*4);   // bit 9
    gate_regbit<1>(amp, G +  9*4);   // bit 10
    gate_regbit<2>(amp, G +  8*4);   // bit 11
    // store logical order; regs = bits 9..11 -> 8 contiguous-512B store instrs
    float2* d = dst + ((size_t)H << 12);
    #pragma unroll
    for (int k = 0; k < 8; k++) d[((unsigned)k << 9) | (wv << 6) | lane] = amp[k];
}

// Stage B: gates on bits 12..19 (wires 7..0); in-place; block = bits 4..11 (bb).
// Thread: m = lane&15 (bits 0..3); high byte h = k | (l45<<3) | (wv<<5):
// regs k = bits 12..14, l45 = bits 15..16, wv = bits 17..19.
// FUSE=1: final layer -> fold last gray perm, accumulate <Z_w> partials (no store).
template<int FUSE>
__global__ __launch_bounds__(512) void stageB(float2* __restrict__ st,
                                              const float2* __restrict__ G,
                                              float* __restrict__ partial) {
    __shared__ float2 lds[4096];
    const unsigned t = threadIdx.x, lane = t & 63u, wv = t >> 6;
    const unsigned bb = blockIdx.x;
    const unsigned m = lane & 15u, l45 = lane >> 4;      // l45: amp bits 15,16 initially

    float2 amp[8];
    #pragma unroll
    for (int k = 0; k < 8; k++) {
        unsigned h = (unsigned)k | (l45 << 3) | (wv << 5);   // FIX: wv<<5 (8-bit h)
        amp[k] = st[((size_t)h << 12) | (bb << 4) | m];
    }
    gate_regbit<0>(amp, G + 7*4);   // bit 12 (wire 7)
    gate_regbit<1>(amp, G + 6*4);   // bit 13
    gate_regbit<2>(amp, G + 5*4);   // bit 14
    swap_reg_lane<0,16>(amp, lane); // bit12 <-> bit15
    swap_reg_lane<1,32>(amp, lane); // bit13 <-> bit16
    gate_regbit<0>(amp, G + 4*4);   // bit 15 (wire 4)
    gate_regbit<1>(amp, G + 3*4);   // bit 16 (wire 3)
    // LDS exchange: regs -> bits 17..19.  At write: b12=lane4 b13=lane5 b14=k2 b15=k0 b16=k1.
    #pragma unroll
    for (int k = 0; k < 8; k++) {
        unsigned li = lane | ((((unsigned)k >> 2) & 1u) << 6) | (((unsigned)k & 1u) << 7)
                    | ((((unsigned)k >> 1) & 1u) << 8) | (wv << 9);
        lds[li] = amp[k];
    }
    __syncthreads();
    #pragma unroll
    for (int k = 0; k < 8; k++) amp[k] = lds[lane | (wv << 6) | ((unsigned)k << 9)];
    // now: b12,b13 = lane4,5 ; b14..16 = wave ; b17..19 = regs
    gate_regbit<0>(amp, G + 2*4);   // bit 17 (wire 2)
    gate_regbit<1>(amp, G + 1*4);   // bit 18 (wire 1)
    gate_regbit<2>(amp, G + 0*4);   // bit 19 (wire 0)

    if (!FUSE) {
        #pragma unroll
        for (int k = 0; k < 8; k++) {
            unsigned h = l45 | (wv << 2) | ((unsigned)k << 5);
            st[((size_t)h << 12) | (bb << 4) | m] = amp[k];
        }
    } else {
        // final perm y = invgray(Y); sign for wire w is y bit (19-w).
        // k = Y bits 17..19 => for b<=16: y_b = C_b ^ parity(k), C_b = XOR_{j=b..16} Y_j.
        float p[8];
        #pragma unroll
        for (int k = 0; k < 8; k++) p[k] = amp[k].x*amp[k].x + amp[k].y*amp[k].y;
        float Se = p[0]+p[3]+p[5]+p[6];                       // parity(k)=0
        float So = p[1]+p[2]+p[4]+p[7];
        float D  = Se - So;
        float S0 = (p[0]+p[1]+p[2]+p[3]) - (p[4]+p[5]+p[6]+p[7]);   // y19 = k2
        float S1 = (p[0]+p[1]+p[6]+p[7]) - (p[2]+p[3]+p[4]+p[5]);   // y18 = k1^k2
        unsigned hlow = l45 | (wv << 2);                      // Y bits 12..16
        unsigned v = (hlow << 12) | (bb << 4) | m;            // Y bits 0..16
        unsigned cm = v; cm ^= cm >> 1; cm ^= cm >> 2; cm ^= cm >> 4;
        cm ^= cm >> 8; cm ^= cm >> 16;                        // cm bit b = C_b
        float acc[NW];
        acc[0] = S0; acc[1] = S1; acc[2] = D;
        #pragma unroll
        for (int w = 3; w < NW; w++)
            acc[w] = ((cm >> (19 - w)) & 1u) ? -D : D;

        __syncthreads();                 // done with gate LDS; reuse for reduction
        float* red = (float*)lds;
        #pragma unroll
        for (int w = 0; w < NW; w++) {
            float s = acc[w];
            #pragma unroll
            for (int off = 32; off; off >>= 1) s += __shfl_down(s, off, 64);
            if (lane == 0) red[wv*NW + w] = s;
        }
        __syncthreads();
        if (t < NW) {
            float s = 0.0f;
            #pragma unroll
            for (int w8 = 0; w8 < 8; w8++) s += red[w8*NW + (int)t];
            partial[bb*NW + t] = s;
        }
    }
}

__global__ __launch_bounds__(256) void reduce_out(const float* __restrict__ partial,
                                                  float* __restrict__ out) {
    __shared__ float red[4*NW];
    unsigned t = threadIdx.x;
    float vals[NW];
    #pragma unroll
    for (int w = 0; w < NW; w++) vals[w] = partial[t*NW + w];
    #pragma unroll
    for (int w = 0; w < NW; w++) {
        float v = vals[w];
        #pragma unroll
        for (int off = 32; off; off >>= 1) v += __shfl_down(v, off, 64);
        if ((t & 63u) == 0u) red[(t >> 6)*NW + w] = v;
    }
    __syncthreads();
    if (t < NW) out[t] = red[t] + red[NW+t] + red[2*NW+t] + red[3*NW+t];
}

extern "C" void kernel_launch(void* const* d_in, const int* in_sizes, int n_in,
                              void* d_out, int out_size, void* d_ws, size_t ws_size,
                              hipStream_t stream) {
    (void)in_sizes; (void)n_in; (void)out_size; (void)ws_size;
    const float* x = (const float*)d_in[0];
    float* out = (float*)d_out;

    char* ws = (char*)d_ws;
    float2* gates   = (float2*)ws;                                // 640 B
    float*  partial = (float*)(ws + 1024);                        // 20 KB
    float2* buf0    = (float2*)(ws + 65536);                      // 8 MB
    float2* buf1    = (float2*)(ws + 65536 + (size_t)(8u << 20)); // 8 MB

    prep_gates<<<1, 32, 0, stream>>>(x, gates);
    // layer 1 folded into product state; layer 2:
    stageA<0><<<256, 512, 0, stream>>>(buf1 /*unused*/, buf0, gates);
    stageB<0><<<256, 512, 0, stream>>>(buf0, gates, nullptr);
    // layer 3 (perm folded into A read):
    stageA<1><<<256, 512, 0, stream>>>(buf0, buf1, gates);
    stageB<0><<<256, 512, 0, stream>>>(buf1, gates, nullptr);
    // layer 4 (+ fused expectation, final perm folded):
    stageA<1><<<256, 512, 0, stream>>>(buf1, buf0, gates);
    stageB<1><<<256, 512, 0, stream>>>(buf0, gates, partial);
    reduce_out<<<1, 256, 0, stream>>>(partial, out);
}